// Round 5
// baseline (164.392 us; speedup 1.0000x reference)
//
#include <hip/hip_runtime.h>
#include <cstdint>

typedef _Float16 half8 __attribute__((ext_vector_type(8)));
typedef float f32x4 __attribute__((ext_vector_type(4)));

#define LN_EPS 1e-5f

__device__ __forceinline__ float dot4(float4 a, float4 b) {
  return a.x*b.x + a.y*b.y + a.z*b.z + a.w*b.w;
}

// ============ K1 (k_pre): blocks 0..255 = mask (1 p-row each); 256..2303 = LN stats.
__global__ __launch_bounds__(256) void k_pre(
    const float* __restrict__ x, const float* __restrict__ few, const float* __restrict__ feb,
    const float* __restrict__ emb_pr, const float* __restrict__ lnp_w, const float* __restrict__ lnp_b,
    const float* __restrict__ prev, const float* __restrict__ W, const float* __restrict__ Wb,
    const float* __restrict__ emb_col, const float* __restrict__ lnc_w, const float* __restrict__ lnc_b,
    float2* __restrict__ stats2, float* __restrict__ mask_f32, _Float16* __restrict__ mask_f16)
{
  __shared__ __align__(16) struct {
    float xin[512];          // [LN(emb_pr[p]) | prev[p]]
    float xq[256];           // x_prompt row
    float sc[256];           // scores
    float wr1[4], wr2[4];
  } sm;

  int t = threadIdx.x, w = t >> 6, lane = t & 63;

  if (blockIdx.x >= 256) {
    // ================= stats role: wave = (b, 8 c-rows), lane = d/4 =================
    int bid = blockIdx.x - 256;
    int b = bid >> 3;
    int cg = (bid & 7) * 4 + w;
    int c0 = cg * 8;
    float xv[8];
    #pragma unroll
    for (int j = 0; j < 8; ++j) xv[j] = x[b*256 + c0 + j];
    float s1[8], s2[8];
    #pragma unroll
    for (int j = 0; j < 8; ++j) { s1[j] = 0.f; s2[j] = 0.f; }
    #pragma unroll
    for (int j = 0; j < 8; ++j) {
      float4 fw = ((const float4*)few)[(c0+j)*64 + lane];
      float4 fb = ((const float4*)feb)[(c0+j)*64 + lane];
      float4 v;
      v.x = fmaxf(fb.x + xv[j]*fw.x, 0.f);
      v.y = fmaxf(fb.y + xv[j]*fw.y, 0.f);
      v.z = fmaxf(fb.z + xv[j]*fw.z, 0.f);
      v.w = fmaxf(fb.w + xv[j]*fw.w, 0.f);
      s1[j] += v.x + v.y + v.z + v.w;
      s2[j] += v.x*v.x + v.y*v.y + v.z*v.z + v.w*v.w;
    }
    #pragma unroll
    for (int o = 32; o > 0; o >>= 1) {
      #pragma unroll
      for (int j = 0; j < 8; ++j) { s1[j] += __shfl_xor(s1[j], o); s2[j] += __shfl_xor(s2[j], o); }
    }
    float mu[8], rs[8];
    #pragma unroll
    for (int j = 0; j < 8; ++j) {
      mu[j] = s1[j] * (1.0f/256.0f);
      float var = s2[j] * (1.0f/256.0f) - mu[j]*mu[j];
      rs[j] = rsqrtf(var + LN_EPS);
    }
    float muv = mu[0], rsv = rs[0];
    #pragma unroll
    for (int j = 1; j < 8; ++j) {
      muv = (lane == j) ? mu[j] : muv;
      rsv = (lane == j) ? rs[j] : rsv;
    }
    if (lane < 8) stats2[b*256 + c0 + lane] = make_float2(muv, rsv);
    return;
  }

  // ================= mask role (p = blockIdx.x) =================
  int p = blockIdx.x;
  int q = t & 3, g = t >> 2;

  // P1: each wave redundantly LNs emb_pr[p]; wave 0 stores [ln|prev] to LDS.
  {
    float4 v = ((const float4*)emb_pr)[p*64 + lane];
    float s1 = v.x + v.y + v.z + v.w;
    float s2 = v.x*v.x + v.y*v.y + v.z*v.z + v.w*v.w;
    #pragma unroll
    for (int o = 32; o > 0; o >>= 1) { s1 += __shfl_xor(s1, o); s2 += __shfl_xor(s2, o); }
    float mu = s1 * (1.0f/256.0f);
    float var = s2 * (1.0f/256.0f) - mu*mu;
    float rsv = rsqrtf(var + LN_EPS);
    float4 w4 = ((const float4*)lnp_w)[lane];
    float4 b4 = ((const float4*)lnp_b)[lane];
    float4 y;
    y.x = (v.x-mu)*rsv*w4.x + b4.x;  y.y = (v.y-mu)*rsv*w4.y + b4.y;
    y.z = (v.z-mu)*rsv*w4.z + b4.z;  y.w = (v.w-mu)*rsv*w4.w + b4.w;
    if (w == 0) {
      ((float4*)sm.xin)[lane] = y;
      ((float4*)sm.xin)[64 + lane] = ((const float4*)prev)[p*64 + lane];
    }
  }
  __syncthreads();

  // P2: x_prompt[d] = sum_k xin[k]*W[d][k] + Wb[d] + emb_pr[p][d]
  {
    float acc[4] = {0.f, 0.f, 0.f, 0.f};
    #pragma unroll 8
    for (int j = 0; j < 32; ++j) {
      int k4 = j*4 + q;
      float4 xv = ((const float4*)sm.xin)[k4];
      #pragma unroll
      for (int pp = 0; pp < 4; ++pp) {
        int d = pp*64 + g;
        float4 wv = ((const float4*)W)[d*128 + k4];
        acc[pp] += dot4(wv, xv);
      }
    }
    #pragma unroll
    for (int pp = 0; pp < 4; ++pp) {
      acc[pp] += __shfl_xor(acc[pp], 1);
      acc[pp] += __shfl_xor(acc[pp], 2);
    }
    if (q == 0) {
      #pragma unroll
      for (int pp = 0; pp < 4; ++pp) {
        int d = pp*64 + g;
        sm.xq[d] = acc[pp] + Wb[d] + emb_pr[p*256 + d];
      }
    }
  }
  __syncthreads();

  // P3: sc[c] = x_prompt . LN(emb_col[c]); in-thread col stats (2 sweeps, 2nd L1-hot).
  {
    float s1[4] = {0,0,0,0}, s2[4] = {0,0,0,0};
    #pragma unroll 8
    for (int j = 0; j < 16; ++j) {
      int k4 = j*4 + q;
      #pragma unroll
      for (int pp = 0; pp < 4; ++pp) {
        float4 v = ((const float4*)emb_col)[(pp*64+g)*64 + k4];
        s1[pp] += v.x + v.y + v.z + v.w;
        s2[pp] += v.x*v.x + v.y*v.y + v.z*v.z + v.w*v.w;
      }
    }
    float mu[4], rs[4];
    #pragma unroll
    for (int pp = 0; pp < 4; ++pp) {
      s1[pp] += __shfl_xor(s1[pp], 1);  s1[pp] += __shfl_xor(s1[pp], 2);
      s2[pp] += __shfl_xor(s2[pp], 1);  s2[pp] += __shfl_xor(s2[pp], 2);
      mu[pp] = s1[pp] * (1.0f/256.0f);
      float var = s2[pp] * (1.0f/256.0f) - mu[pp]*mu[pp];
      rs[pp] = rsqrtf(var + LN_EPS);
    }
    float acc[4] = {0.f, 0.f, 0.f, 0.f};
    #pragma unroll 8
    for (int j = 0; j < 16; ++j) {
      int k4 = j*4 + q;
      float4 lw4 = ((const float4*)lnc_w)[k4];
      float4 lb4 = ((const float4*)lnc_b)[k4];
      float4 xv = ((const float4*)sm.xq)[k4];
      #pragma unroll
      for (int pp = 0; pp < 4; ++pp) {
        float4 v = ((const float4*)emb_col)[(pp*64+g)*64 + k4];
        float4 nc;
        nc.x = (v.x-mu[pp])*rs[pp]*lw4.x + lb4.x;
        nc.y = (v.y-mu[pp])*rs[pp]*lw4.y + lb4.y;
        nc.z = (v.z-mu[pp])*rs[pp]*lw4.z + lb4.z;
        nc.w = (v.w-mu[pp])*rs[pp]*lw4.w + lb4.w;
        acc[pp] += dot4(nc, xv);
      }
    }
    #pragma unroll
    for (int pp = 0; pp < 4; ++pp) {
      acc[pp] += __shfl_xor(acc[pp], 1);
      acc[pp] += __shfl_xor(acc[pp], 2);
    }
    if (q == 0) {
      #pragma unroll
      for (int pp = 0; pp < 4; ++pp) sm.sc[pp*64 + g] = acc[pp];
    }
  }
  __syncthreads();

  // P4: softmax over 256 c
  {
    float val = sm.sc[t];
    float m0 = val;
    #pragma unroll
    for (int o = 32; o > 0; o >>= 1) m0 = fmaxf(m0, __shfl_xor(m0, o));
    if (lane == 0) sm.wr1[w] = m0;
    __syncthreads();
    float M = fmaxf(fmaxf(sm.wr1[0], sm.wr1[1]), fmaxf(sm.wr1[2], sm.wr1[3]));
    float e = expf(val - M);
    float s = e;
    #pragma unroll
    for (int o = 32; o > 0; o >>= 1) s += __shfl_xor(s, o);
    if (lane == 0) sm.wr2[w] = s;
    __syncthreads();
    float S = sm.wr2[0] + sm.wr2[1] + sm.wr2[2] + sm.wr2[3];
    float mv = e / S;
    mask_f32[p*256 + t] = mv;
    mask_f16[p*256 + t] = (_Float16)mv;
  }
}

// ============ K2 (k_main): fused x_emb producer + GEMM + epilogue, software-pipelined.
// Tile M=256 (all p) x N=64 (one b, one 64-d slab), K=256 (c). 1024 blocks.
// Round-4 post-mortem: producer L2 loads were issued right before use (latency exposed,
// VALUBusy 14%). Now: few/feb for chunk k+1 issued at chunk k (land during barrier+MFMA),
// A-fragments issued before pf so the MFMA's vmcnt wait leaves pf in flight,
// double-buffered Bs -> 1 barrier/chunk (5 total, was 9), nontemporal out stores.
__global__ __launch_bounds__(256) void k_main(
    const float* __restrict__ x, const float* __restrict__ few, const float* __restrict__ feb,
    const float* __restrict__ ln_emb_w, const float* __restrict__ ln_emb_b,
    const float2* __restrict__ stats2,
    const _Float16* __restrict__ mask_f16, const float* __restrict__ mask_f32,
    const float* __restrict__ ew, const float* __restrict__ eb,
    float* __restrict__ out)
{
  __shared__ __align__(16) _Float16 Bs[2][8 * 64 * 8];   // 2 x 8 KB, [k8][n][8]
  __shared__ float xrow[256];
  __shared__ float2 srow[256];

  int t = threadIdx.x, w = t >> 6, lane = t & 63;
  int lm = lane & 15, quad = lane >> 4;
  int b = blockIdx.x >> 2;
  int ds = (blockIdx.x & 3) * 64;
  int dl = t & 63;

  xrow[t] = x[b*256 + t];
  srow[t] = stats2[b*256 + t];
  float lwv = ln_emb_w[ds + dl];
  float lbv = ln_emb_b[ds + dl];

  // prologue prefetch: chunk 0 few/feb (independent of LDS)
  float pfw[16], pfb[16];
  #pragma unroll
  for (int j = 0; j < 16; ++j) {
    int cl = w*16 + j;
    pfw[j] = few[cl*256 + ds + dl];
    pfb[j] = feb[cl*256 + ds + dl];
  }

  f32x4 acc[4][4];
  #pragma unroll
  for (int i = 0; i < 4; ++i)
    #pragma unroll
    for (int j = 0; j < 4; ++j)
      acc[i][j] = (f32x4){0.f, 0.f, 0.f, 0.f};

  __syncthreads();   // xrow/srow visible

  #pragma unroll
  for (int kb = 0; kb < 4; ++kb) {
    int cur = kb & 1;
    // --- consume pf into fp16 h (LDS xrow/srow reads are wave-uniform broadcasts)
    half8 h0, h1;
    #pragma unroll
    for (int j = 0; j < 16; ++j) {
      int cl = kb*64 + w*16 + j;
      float xc = xrow[cl];
      float2 st = srow[cl];
      float v = fmaxf(pfb[j] + xc*pfw[j], 0.f);
      _Float16 hh = (_Float16)((v - st.x) * st.y * lwv + lbv);
      if (j < 8) h0[j] = hh; else h1[j-8] = hh;
    }
    // --- A-fragments for this chunk (global, L2-hot) BEFORE pf reload:
    //     MFMA's wait on af leaves the newer pf loads outstanding.
    half8 af[2][4];
    #pragma unroll
    for (int ks = 0; ks < 2; ++ks)
      #pragma unroll
      for (int mt = 0; mt < 4; ++mt)
        af[ks][mt] = *(const half8*)(mask_f16 + (size_t)(w*64 + mt*16 + lm)*256 + kb*64 + ks*32 + quad*8);
    // --- prefetch chunk kb+1 few/feb into the (now free) pf regs
    if (kb < 3) {
      #pragma unroll
      for (int j = 0; j < 16; ++j) {
        int cl = (kb+1)*64 + w*16 + j;
        pfw[j] = few[cl*256 + ds + dl];
        pfb[j] = feb[cl*256 + ds + dl];
      }
    }
    // --- stage B tile (conflict-free [k8][n][8])
    *(half8*)(Bs[cur] + ((w*2 + 0)*64 + dl)*8) = h0;
    *(half8*)(Bs[cur] + ((w*2 + 1)*64 + dl)*8) = h1;
    __syncthreads();

    #pragma unroll
    for (int ks = 0; ks < 2; ++ks) {
      half8 bf[4];
      #pragma unroll
      for (int nt = 0; nt < 4; ++nt)
        bf[nt] = *(const half8*)(Bs[cur] + ((ks*4 + quad)*64 + nt*16 + lm)*8);
      #pragma unroll
      for (int mt = 0; mt < 4; ++mt)
        #pragma unroll
        for (int nt = 0; nt < 4; ++nt)
          acc[mt][nt] = __builtin_amdgcn_mfma_f32_16x16x32_f16(af[ks][mt], bf[nt], acc[mt][nt], 0, 0, 0);
    }
    // no trailing barrier: next chunk writes the other Bs buffer; barrier k+1 bounds skew
  }

  // epilogue: C/D layout col=lane&15 (d), row=quad*4+r (p); nontemporal streaming stores
  float ebv = eb[b];
  #pragma unroll
  for (int mt = 0; mt < 4; ++mt) {
    float sp[4], tb[4];
    #pragma unroll
    for (int r = 0; r < 4; ++r) {
      int p = w*64 + mt*16 + quad*4 + r;
      sp[r] = 1.0f + ew[p];
      tb[r] = mask_f32[b*256 + p] * ebv;
    }
    #pragma unroll
    for (int nt = 0; nt < 4; ++nt) {
      int d = ds + nt*16 + lm;
      #pragma unroll
      for (int r = 0; r < 4; ++r) {
        int p = w*64 + mt*16 + quad*4 + r;
        __builtin_nontemporal_store(acc[mt][nt][r] * sp[r] + tb[r],
                                    out + ((size_t)b << 16) + ((size_t)p << 8) + d);
      }
    }
  }
}

extern "C" void kernel_launch(void* const* d_in, const int* in_sizes, int n_in,
                              void* d_out, int out_size, void* d_ws, size_t ws_size,
                              hipStream_t stream) {
  const float* x        = (const float*)d_in[0];
  const float* prev     = (const float*)d_in[1];
  const float* few      = (const float*)d_in[2];
  const float* feb      = (const float*)d_in[3];
  const float* ln_emb_w = (const float*)d_in[4];
  const float* ln_emb_b = (const float*)d_in[5];
  const float* ln_col_w = (const float*)d_in[6];
  const float* ln_col_b = (const float*)d_in[7];
  const float* ln_pr_w  = (const float*)d_in[8];
  const float* ln_pr_b  = (const float*)d_in[9];
  const float* dimp_w   = (const float*)d_in[10];
  const float* dimp_b   = (const float*)d_in[11];
  const float* emb_col  = (const float*)d_in[12];
  const float* emb_pr   = (const float*)d_in[13];
  const float* ew       = (const float*)d_in[14];
  const float* eb       = (const float*)d_in[15];
  float* out = (float*)d_out;

  char* wsb = (char*)d_ws;
  float2*   ws_stats  = (float2*)(wsb);                  // 524,288 B
  float*    ws_mask   = (float*)(wsb + 524288);          // 262,144 B
  _Float16* ws_mask_h = (_Float16*)(wsb + 786432);       // 131,072 B

  k_pre<<<dim3(256 + 2048), dim3(256), 0, stream>>>(
      x, few, feb,
      emb_pr, ln_pr_w, ln_pr_b, prev, dimp_w, dimp_b,
      emb_col, ln_col_w, ln_col_b,
      ws_stats, ws_mask, ws_mask_h);
  k_main<<<dim3(1024), dim3(256), 0, stream>>>(
      x, few, feb, ln_emb_w, ln_emb_b,
      ws_stats, ws_mask_h, ws_mask, ew, eb, out);
}